// Round 4
// baseline (17.498 us; speedup 1.0000x reference)
//
#include <hip/hip_runtime.h>

// Analytic collapse of the 4-qubit RY + CNOT-ring circuit:
//   <Z0> = c1*c2*c3, <Z1> = c0*c1, <Z2> = c0*c1*c2, <Z3> = c0*c1*c2*c3
// where ci = cos(theta_i).
//
// Memory-bound: 32 MiB in + 32 MiB out, zero reuse. 8 float4/thread strided
// (coalesced), all loads issued unconditionally back-to-back (exact-fit
// specialization removes bounds checks), nontemporal stores.

typedef float f32x4 __attribute__((ext_vector_type(4)));

#define EPT 8  // float4 elements per thread

__device__ __forceinline__ f32x4 qqf_compute(f32x4 t) {
    float c0 = __cosf(t.x);
    float c1 = __cosf(t.y);
    float c2 = __cosf(t.z);
    float c3 = __cosf(t.w);
    f32x4 o;
    o.y = c0 * c1;        // <Z1>
    o.z = o.y * c2;       // <Z2>
    o.w = o.z * c3;       // <Z3>
    o.x = c1 * c2 * c3;   // <Z0>
    return o;
}

// Exact-fit fast path: no bounds checks, 8 unconditional loads in flight.
__global__ __launch_bounds__(256) void qqf_exact(const f32x4* __restrict__ x,
                                                 f32x4* __restrict__ out) {
    int tid = blockIdx.x * blockDim.x + threadIdx.x;
    int nthreads = gridDim.x * blockDim.x;

    f32x4 t[EPT];
    #pragma unroll
    for (int u = 0; u < EPT; ++u)
        t[u] = __builtin_nontemporal_load(&x[tid + u * nthreads]);

    #pragma unroll
    for (int u = 0; u < EPT; ++u)
        __builtin_nontemporal_store(qqf_compute(t[u]), &out[tid + u * nthreads]);
}

// Generic fallback with bounds checks.
__global__ __launch_bounds__(256) void qqf_bounded(const f32x4* __restrict__ x,
                                                   f32x4* __restrict__ out, int B) {
    int tid = blockIdx.x * blockDim.x + threadIdx.x;
    int nthreads = gridDim.x * blockDim.x;
    for (int b = tid; b < B; b += nthreads)
        __builtin_nontemporal_store(qqf_compute(__builtin_nontemporal_load(&x[b])),
                                    &out[b]);
}

extern "C" void kernel_launch(void* const* d_in, const int* in_sizes, int n_in,
                              void* d_out, int out_size, void* d_ws, size_t ws_size,
                              hipStream_t stream) {
    const f32x4* x = (const f32x4*)d_in[0];
    f32x4* out = (f32x4*)d_out;
    int B = in_sizes[0] / 4;   // [B,4] float32 -> B float4 rows
    const int block = 256;
    const int chunk = block * EPT;
    if (B % chunk == 0) {
        qqf_exact<<<B / chunk, block, 0, stream>>>(x, out);
    } else {
        int grid = (B + block - 1) / block;
        if (grid > 2048) grid = 2048;
        qqf_bounded<<<grid, block, 0, stream>>>(x, out, B);
    }
}

// Round 5
// 15.118 us; speedup vs baseline: 1.1574x; 1.1574x over previous
//
#include <hip/hip_runtime.h>

// Analytic collapse of the 4-qubit RY + CNOT-ring circuit:
//   <Z0> = c1*c2*c3, <Z1> = c0*c1, <Z2> = c0*c1*c2, <Z3> = c0*c1*c2*c3
// where ci = cos(theta_i).
//
// Memory-bound streaming: 32 MiB in + 32 MiB out. Floor = ~10.2 us transfer
// at 6.5 TB/s (harness fill rate) + ~4.5 us fixed launch/ramp overhead.
// Schedule: EPT=4, 2048 blocks (8 waves/SIMD for TLP), exact-fit removes
// bounds checks -> 4 unconditional coalesced dwordx4 loads in flight.

typedef float f32x4 __attribute__((ext_vector_type(4)));

#define EPT 4  // float4 elements per thread

__device__ __forceinline__ f32x4 qqf_compute(f32x4 t) {
    float c0 = __cosf(t.x);
    float c1 = __cosf(t.y);
    float c2 = __cosf(t.z);
    float c3 = __cosf(t.w);
    f32x4 o;
    o.y = c0 * c1;        // <Z1>
    o.z = o.y * c2;       // <Z2>
    o.w = o.z * c3;       // <Z3>
    o.x = c1 * c2 * c3;   // <Z0>
    return o;
}

// Exact-fit fast path: no bounds checks.
__global__ __launch_bounds__(256) void qqf_exact(const f32x4* __restrict__ x,
                                                 f32x4* __restrict__ out) {
    int tid = blockIdx.x * blockDim.x + threadIdx.x;
    int nthreads = gridDim.x * blockDim.x;

    f32x4 t[EPT];
    #pragma unroll
    for (int u = 0; u < EPT; ++u)
        t[u] = x[tid + u * nthreads];

    #pragma unroll
    for (int u = 0; u < EPT; ++u)
        __builtin_nontemporal_store(qqf_compute(t[u]), &out[tid + u * nthreads]);
}

// Generic fallback with bounds checks.
__global__ __launch_bounds__(256) void qqf_bounded(const f32x4* __restrict__ x,
                                                   f32x4* __restrict__ out, int B) {
    int tid = blockIdx.x * blockDim.x + threadIdx.x;
    int nthreads = gridDim.x * blockDim.x;
    for (int b = tid; b < B; b += nthreads)
        __builtin_nontemporal_store(qqf_compute(x[b]), &out[b]);
}

extern "C" void kernel_launch(void* const* d_in, const int* in_sizes, int n_in,
                              void* d_out, int out_size, void* d_ws, size_t ws_size,
                              hipStream_t stream) {
    const f32x4* x = (const f32x4*)d_in[0];
    f32x4* out = (f32x4*)d_out;
    int B = in_sizes[0] / 4;   // [B,4] float32 -> B float4 rows
    const int block = 256;
    const int chunk = block * EPT;
    if (B % chunk == 0) {
        qqf_exact<<<B / chunk, block, 0, stream>>>(x, out);
    } else {
        int grid = (B + block - 1) / block;
        if (grid > 2048) grid = 2048;
        qqf_bounded<<<grid, block, 0, stream>>>(x, out, B);
    }
}